// Round 14
// baseline (735.903 us; speedup 1.0000x reference)
//
#include <hip/hip_runtime.h>
#include <cstdint>
#include <cstddef>

typedef float f32x4 __attribute__((ext_vector_type(4)));
typedef __bf16 bf16x8 __attribute__((ext_vector_type(8)));
typedef __bf16 bf16x4 __attribute__((ext_vector_type(4)));
typedef unsigned short u16;

#define Hdim 128
#define DEdim 16
#define TP 40          // tail pitch (u16): [ea(16) | radial | zeros..31], 80B rows

__device__ __forceinline__ float bf2f(uint32_t lo16){
  return __builtin_bit_cast(float, lo16 << 16);
}
__device__ __forceinline__ float bfhi(uint32_t v){
  return __builtin_bit_cast(float, v & 0xffff0000u);
}
// fast silu: v_mul, v_exp, v_add, v_rcp, v_mul (avoids IEEE div expansion)
__device__ __forceinline__ float silu_f(float x){
  return x * __builtin_amdgcn_rcpf(1.0f + __expf(-x));
}
__device__ __forceinline__ uint2 pack4(f32x4 v){
  bf16x4 p;
  #pragma unroll
  for (int i=0;i<4;++i) p[i] = (__bf16)v[i];
  return __builtin_bit_cast(uint2, p);
}
__device__ __forceinline__ uint2 silu_pack4(const f32x4& v, f32x4* sout=nullptr){
  f32x4 s;
  #pragma unroll
  for (int i=0;i<4;++i) s[i] = silu_f(v[i]);
  if (sout) *sout = s;
  return pack4(s);
}

// Swapped-operand tile GEMM: OUT[f][e] = W(16f x K) x IN(K x 16e), ET edge-tiles x 2 feature-tiles.
// arg0 (A-op) = weight frag: lane holds Wt[ftile*16 + (lane&15)][k], k=(lane>>4)*8+slot
// arg1 (B-op) = input frag:  lane holds IN[k][etile*16 + (lane&15)] = LDS[e][k]
// D: reg i -> feature f = ftile*16 + (lane>>4)*4 + i, edge e = etile*16 + (lane&15)
template<int KC, int ET>
__device__ __forceinline__ void gemm_sw(
    const u16* A, int apitch,
    const u16* __restrict__ Wt, int kpad, int woff,
    int wv, int cidx, int hi, f32x4 (&acc)[ET][2])
{
  const u16* w0p = Wt + (size_t)((wv*2+0)*16 + cidx)*kpad + woff + hi*8;
  const u16* w1p = Wt + (size_t)((wv*2+1)*16 + cidx)*kpad + woff + hi*8;
  const u16* ap  = A + (size_t)cidx*apitch + hi*8;
  #pragma unroll
  for (int kc=0; kc<KC; ++kc){
    bf16x8 w0 = *(const bf16x8*)(w0p + kc*32);
    bf16x8 w1 = *(const bf16x8*)(w1p + kc*32);
    #pragma unroll
    for (int et=0; et<ET; ++et){
      bf16x8 a = *(const bf16x8*)(ap + et*16*apitch + kc*32);
      acc[et][0] = __builtin_amdgcn_mfma_f32_16x16x32_bf16(w0, a, acc[et][0], 0,0,0);
      acc[et][1] = __builtin_amdgcn_mfma_f32_16x16x32_bf16(w1, a, acc[et][1], 0,0,0);
    }
  }
}

template<int ET>
__device__ __forceinline__ void acc_bias(const float* __restrict__ bias,
                                         int wv, int hi, f32x4 (&acc)[ET][2])
{
  f32x4 b0 = *(const f32x4*)(bias + (wv*2+0)*16 + hi*4);
  f32x4 b1 = *(const f32x4*)(bias + (wv*2+1)*16 + hi*4);
  #pragma unroll
  for (int et=0;et<ET;++et){ acc[et][0]=b0; acc[et][1]=b1; }
}

template<int SP, int ET>
__device__ __forceinline__ void write_silu_S(u16* S, f32x4 (&acc)[ET][2],
                                             int wv, int cidx, int hi)
{
  #pragma unroll
  for (int et=0; et<ET; ++et){
    const int e = et*16 + cidx;
    #pragma unroll
    for (int j=0;j<2;++j){
      const int f0 = (wv*2+j)*16 + hi*4;
      *(uint2*)(S + (size_t)e*SP + f0) = silu_pack4(acc[et][j]);
    }
  }
}

// Register ledger (measured r3/r7/r8/r10/r12): ET=4 live state ~110-125 unified
// VGPR+AGPR -> only the 128-reg tier (4 w/SIMD) works. ET=2 halves acc/gather/ps
// (~-40 regs) -> ~75-90 live, targeting the 102-reg tier (5 w/SIMD, 62% occ).
// Tripwire: WRITE_SIZE > ~780 MB = spill -> revert to ET=4 @ 4 w/SIMD.
template<bool PROJ, bool GATHER>
__global__ __launch_bounds__(256, PROJ?5:3) void egcl_edge(
    const float* __restrict__ h, const float* __restrict__ coord,
    const int* __restrict__ ei, const float* __restrict__ ea,
    const u16* __restrict__ projf, const int* __restrict__ pos,
    const float* __restrict__ mes_b1, const float* __restrict__ mes_b2,
    const float* __restrict__ edge_b1, const float* __restrict__ edge_b2,
    const float* __restrict__ coord_b1, const float* __restrict__ coord_w2,
    const u16* __restrict__ w_mes1t, const u16* __restrict__ w_mes2t,
    const u16* __restrict__ w_coord1t, const u16* __restrict__ w_edge1t,
    const u16* __restrict__ w_edge2t,
    float* __restrict__ agg, u16* __restrict__ featb,
    float* __restrict__ out_coord, float* __restrict__ out_edge, int E)
{
  constexpr int ET   = PROJ ? 2 : 4;
  constexpr int ROWS = ET*16;
  constexpr int SP   = PROJ ? 136 : 264;   // 272B / 528B rows: conflict-free b128
  __shared__ u16 S[ROWS*SP];
  __shared__ u16 T[ROWS*TP];
  __shared__ float cds[ROWS*4];
  __shared__ float tvs[4][ROWS];
  __shared__ int cnode[ROWS];

  const int tid  = threadIdx.x;
  const int lane = tid & 63;
  const int wv   = tid >> 6;
  const int e0   = blockIdx.x * ROWS;
  const int cidx = lane & 15;
  const int hi   = lane >> 4;

  // ---------- early-issued proj gathers (bf16): latency overlaps stage+B1 ----------
  ushort4 gr[ET][2], gc[ET][2];
  if constexpr (PROJ){
    #pragma unroll
    for (int et=0;et<ET;++et){
      int eg = e0 + et*16 + cidx; if (eg >= E) eg = E-1;
      const int rn = ei[eg], cn = ei[E + eg];
      const u16* pr = projf + (size_t)rn*256 + wv*32 + hi*4;
      const u16* pc = projf + (size_t)cn*256 + 128 + wv*32 + hi*4;
      gr[et][0] = *(const ushort4*)(pr);
      gr[et][1] = *(const ushort4*)(pr + 16);
      gc[et][0] = *(const ushort4*)(pc);
      gc[et][1] = *(const ushort4*)(pc + 16);
    }
  }

  // ---------- stage ----------
  if constexpr (!PROJ){
    const int le   = wv*16 + (lane>>2);
    const int part = lane & 3;
    int eg = e0 + le; if (eg >= E) eg = E-1;
    const int rn = ei[eg], cn = ei[E + eg];
    // S[e][0..128) = h[rn] bf16, [128..256) = h[cn]
    const float* src = ((part<2) ? h + (size_t)rn*Hdim : h + (size_t)cn*Hdim) + (part&1)*64;
    u16* dst = S + (size_t)le*SP + part*64;
    #pragma unroll
    for (int q=0;q<16;++q){
      float4 v = ((const float4*)src)[q];
      bf16x4 o = {(__bf16)v.x,(__bf16)v.y,(__bf16)v.z,(__bf16)v.w};
      *(bf16x4*)(dst + q*4) = o;
    }
  }
  if (tid < ROWS){
    const int le = tid;
    int eg = e0 + le; if (eg >= E) eg = E-1;
    const int rn = ei[eg], cn = ei[E + eg];
    cnode[le] = cn;
    const float dx = coord[(size_t)rn*3+0] - coord[(size_t)cn*3+0];
    const float dy = coord[(size_t)rn*3+1] - coord[(size_t)cn*3+1];
    const float dz = coord[(size_t)rn*3+2] - coord[(size_t)cn*3+2];
    const float radial = dx*dx + dy*dy + dz*dz;
    const float inv = __builtin_amdgcn_rcpf(sqrtf(radial + 1e-8f) + 1.0f);
    cds[le*4+0]=dx*inv; cds[le*4+1]=dy*inv; cds[le*4+2]=dz*inv; cds[le*4+3]=radial;
    u16* tp = T + le*TP;
    const float4* eap = (const float4*)(ea + (size_t)eg*DEdim);
    #pragma unroll
    for (int q=0;q<4;++q){
      float4 v = eap[q];
      bf16x4 o = {(__bf16)v.x,(__bf16)v.y,(__bf16)v.z,(__bf16)v.w};
      *(bf16x4*)(tp + q*4) = o;
    }
    bf16x4 z = {(__bf16)0.f,(__bf16)0.f,(__bf16)0.f,(__bf16)0.f};
    *(bf16x4*)(tp+16) = z; *(bf16x4*)(tp+20) = z;
    *(bf16x4*)(tp+24) = z; *(bf16x4*)(tp+28) = z;
    *(__bf16*)(tp+16) = (__bf16)radial;       // T col16 = radial (after zeros)
  }
  __syncthreads();                                   // B1

  f32x4 acc[ET][2];

  // ---------- mes layer 1 ----------
  acc_bias<ET>(mes_b1, wv, hi, acc);
  if constexpr (PROJ){
    #pragma unroll
    for (int et=0;et<ET;++et){
      #pragma unroll
      for (int j=0;j<2;++j){
        acc[et][j][0] += bf2f(gr[et][j].x) + bf2f(gc[et][j].x);
        acc[et][j][1] += bf2f(gr[et][j].y) + bf2f(gc[et][j].y);
        acc[et][j][2] += bf2f(gr[et][j].z) + bf2f(gc[et][j].z);
        acc[et][j][3] += bf2f(gr[et][j].w) + bf2f(gc[et][j].w);
      }
    }
    gemm_sw<1,ET>(T, TP, w_mes1t, 288, 256, wv, cidx, hi, acc);
  } else {
    gemm_sw<8,ET>(S, SP, w_mes1t, 288, 0,   wv, cidx, hi, acc);
    gemm_sw<1,ET>(T, TP, w_mes1t, 288, 256, wv, cidx, hi, acc);
    __syncthreads();   // S K-reads done before overwriting cols [0,128)
  }
  write_silu_S<SP,ET>(S, acc, wv, cidx, hi);
  __syncthreads();                                   // B2

  // ---------- mes layer 2 -> edge_feat ----------
  acc_bias<ET>(mes_b2, wv, hi, acc);
  gemm_sw<4,ET>(S, SP, w_mes2t, 128, 0, wv, cidx, hi, acc);
  uint2 ps[ET][2];
  #pragma unroll
  for (int et=0;et<ET;++et)
    #pragma unroll
    for (int j=0;j<2;++j){
      f32x4 sv;
      ps[et][j] = silu_pack4(acc[et][j], &sv);
      if constexpr (!GATHER){
        const int e = et*16 + cidx;
        if (e0 + e < E){
          const int f0 = (wv*2+j)*16 + hi*4;
          #pragma unroll
          for (int i=0;i<4;++i)
            atomicAdd(agg + (size_t)cnode[e]*Hdim + f0 + i, sv[i]);
        }
      }
    }
  __syncthreads();                                   // B3 (S K-reads done)
  #pragma unroll
  for (int et=0;et<ET;++et)
    #pragma unroll
    for (int j=0;j<2;++j)
      *(uint2*)(S + (size_t)(et*16+cidx)*SP + (wv*2+j)*16 + hi*4) = ps[et][j];
  __syncthreads();                                   // B4

  if constexpr (GATHER){
    // stream feat row to its CSR slot, coalesced (TPR threads x CH u16 per row)
    constexpr int TPR = 256/ROWS;           // 8 (ET=2) or 4 (ET=4)
    constexpr int CH  = 128/TPR;            // 16 or 32 u16 per thread
    const int row = tid / TPR, seg = tid % TPR;
    if (e0 + row < E){
      const int4* s = (const int4*)(S + (size_t)row*SP + seg*CH);
      int4* d = (int4*)(featb + (size_t)pos[e0+row]*Hdim + seg*CH);
      #pragma unroll
      for (int q=0;q<CH/8;++q) d[q] = s[q];
    }
  }

  // ---------- coord layer ----------
  acc_bias<ET>(coord_b1, wv, hi, acc);
  gemm_sw<4,ET>(S, SP, w_coord1t, 128, 0, wv, cidx, hi, acc);
  {
    f32x4 cw0 = *(const f32x4*)(coord_w2 + (wv*2+0)*16 + hi*4);
    f32x4 cw1 = *(const f32x4*)(coord_w2 + (wv*2+1)*16 + hi*4);
    #pragma unroll
    for (int et=0;et<ET;++et){
      float p = 0.f;
      #pragma unroll
      for (int i=0;i<4;++i)
        p += silu_f(acc[et][0][i])*cw0[i] + silu_f(acc[et][1][i])*cw1[i];
      p += __shfl_xor(p, 16);
      p += __shfl_xor(p, 32);
      if (hi == 0) tvs[wv][et*16+cidx] = p;
    }
  }

  // ---------- edge layer 1 ----------
  acc_bias<ET>(edge_b1, wv, hi, acc);
  gemm_sw<4,ET>(S, SP, w_edge1t, 160, 0,   wv, cidx, hi, acc);
  gemm_sw<1,ET>(T, TP, w_edge1t, 160, 128, wv, cidx, hi, acc);
  #pragma unroll
  for (int et=0;et<ET;++et)
    #pragma unroll
    for (int j=0;j<2;++j)
      ps[et][j] = silu_pack4(acc[et][j]);
  __syncthreads();                                   // B5 (tvs ready; S K-reads done)
  #pragma unroll
  for (int et=0;et<ET;++et)
    #pragma unroll
    for (int j=0;j<2;++j)
      *(uint2*)(S + (size_t)(et*16+cidx)*SP + (wv*2+j)*16 + hi*4) = ps[et][j];
  __syncthreads();                                   // B6

  // ---------- edge layer 2 (no activation) ----------
  acc_bias<ET>(edge_b2, wv, hi, acc);
  gemm_sw<4,ET>(S, SP, w_edge2t, 128, 0, wv, cidx, hi, acc);
  #pragma unroll
  for (int et=0;et<ET;++et){
    const int e = e0 + et*16 + cidx;
    if (e < E){
      #pragma unroll
      for (int j=0;j<2;++j)
        *(f32x4*)(out_edge + (size_t)e*Hdim + (wv*2+j)*16 + hi*4) = acc[et][j];
    }
  }

  // ---------- coord scatter (after last barrier: contended-atomic drain
  // overlaps block teardown instead of sitting inside the barrier chain) ----------
  if (tid < ROWS*3){
    const int le = tid/3, d = tid - le*3;
    if (e0 + le < E){
      const float t4 = tvs[0][le]+tvs[1][le]+tvs[2][le]+tvs[3][le];
      atomicAdd(out_coord + (size_t)cnode[le]*3 + d, cds[le*4+d]*t4);
    }
  }
}

// proj[n][half*128+f] = sum_k h[n][k] * mes_w1[half*128+k][f]   (bf16 out)
__global__ __launch_bounds__(256, 4) void egcl_proj(
    const float* __restrict__ h, const u16* __restrict__ w_mes1t,
    u16* __restrict__ proj, int N)
{
  __shared__ u16 S[64*136];
  const int tid=threadIdx.x, lane=tid&63, wv=tid>>6, cidx=lane&15, hi=lane>>4;
  const int r0 = blockIdx.x*64, half = blockIdx.y;
  {
    const int le = tid>>2, part = tid&3;
    int g = r0 + le; if (g >= N) g = N-1;
    const float* src = h + (size_t)g*Hdim + part*32;
    u16* dst = S + (size_t)le*136 + part*32;
    #pragma unroll
    for (int q=0;q<8;++q){
      float4 v = ((const float4*)src)[q];
      bf16x4 o = {(__bf16)v.x,(__bf16)v.y,(__bf16)v.z,(__bf16)v.w};
      *(bf16x4*)(dst + q*4) = o;
    }
  }
  __syncthreads();
  f32x4 acc[4][2];
  #pragma unroll
  for (int et=0;et<4;++et){ acc[et][0]=(f32x4){0,0,0,0}; acc[et][1]=(f32x4){0,0,0,0}; }
  gemm_sw<4,4>(S, 136, w_mes1t, 288, half*128, wv, cidx, hi, acc);
  #pragma unroll
  for (int et=0;et<4;++et){
    const int g = r0 + et*16 + cidx;
    if (g < N){
      #pragma unroll
      for (int j=0;j<2;++j)
        *(uint2*)(proj + (size_t)g*256 + half*128 + (wv*2+j)*16 + hi*4) = pack4(acc[et][j]);
    }
  }
}

template<bool GATHER>
__global__ __launch_bounds__(256, 4) void egcl_node(
    const float* __restrict__ h, const float* __restrict__ agg,
    const int* __restrict__ offs, const int* __restrict__ deg,
    const u16* __restrict__ featb,
    const float* __restrict__ node_b1, const float* __restrict__ node_b2,
    const u16* __restrict__ w_node1t, const u16* __restrict__ w_node2t,
    float* __restrict__ out_h, int N)
{
  __shared__ u16 Ab[64*264];
  const int tid=threadIdx.x, lane=tid&63, wv=tid>>6, cidx=lane&15, hi=lane>>4;
  const int r0 = blockIdx.x*64;
  // stage h -> cols [0,128)
  {
    const int le = tid>>2, part = tid&3;
    int g = r0 + le; if (g >= N) g = N-1;
    const float* src = h + (size_t)g*Hdim + part*32;
    u16* dst = Ab + (size_t)le*264 + part*32;
    #pragma unroll
    for (int q=0;q<8;++q){
      float4 v = ((const float4*)src)[q];
      bf16x4 o = {(__bf16)v.x,(__bf16)v.y,(__bf16)v.z,(__bf16)v.w};
      *(bf16x4*)(dst + q*4) = o;
    }
  }
  // agg -> cols [128,256)
  if constexpr (GATHER){
    const int le = tid>>2, part = tid&3;
    const int g = r0 + le;
    float a[32];
    #pragma unroll
    for (int q=0;q<32;++q) a[q]=0.f;
    if (g < N){
      const int s = offs[g], dg = deg[g];
      const u16* base = featb + (size_t)s*Hdim + part*32;
      #pragma unroll 2
      for (int r=0;r<dg;++r){
        const uint4* rp = (const uint4*)(base + (size_t)r*Hdim);
        #pragma unroll
        for (int q=0;q<4;++q){
          uint4 w = rp[q];
          a[q*8+0] += bf2f(w.x & 0xffffu); a[q*8+1] += bfhi(w.x);
          a[q*8+2] += bf2f(w.y & 0xffffu); a[q*8+3] += bfhi(w.y);
          a[q*8+4] += bf2f(w.z & 0xffffu); a[q*8+5] += bfhi(w.z);
          a[q*8+6] += bf2f(w.w & 0xffffu); a[q*8+7] += bfhi(w.w);
        }
      }
    }
    u16* dst = Ab + (size_t)le*264 + 128 + part*32;
    #pragma unroll
    for (int q=0;q<8;++q){
      bf16x4 o = {(__bf16)a[q*4+0],(__bf16)a[q*4+1],(__bf16)a[q*4+2],(__bf16)a[q*4+3]};
      *(bf16x4*)(dst + q*4) = o;
    }
  } else {
    const int le = tid>>2, part = tid&3;
    int g = r0 + le; if (g >= N) g = N-1;
    const float* src = agg + (size_t)g*Hdim + part*32;
    u16* dst = Ab + (size_t)le*264 + 128 + part*32;
    #pragma unroll
    for (int q=0;q<8;++q){
      float4 v = ((const float4*)src)[q];
      bf16x4 o = {(__bf16)v.x,(__bf16)v.y,(__bf16)v.z,(__bf16)v.w};
      *(bf16x4*)(dst + q*4) = o;
    }
  }
  __syncthreads();

  f32x4 acc[4][2];
  acc_bias<4>(node_b1, wv, hi, acc);
  gemm_sw<8,4>(Ab, 264, w_node1t, 256, 0, wv, cidx, hi, acc);
  __syncthreads();
  write_silu_S<264,4>(Ab, acc, wv, cidx, hi);
  __syncthreads();
  acc_bias<4>(node_b2, wv, hi, acc);
  gemm_sw<4,4>(Ab, 264, w_node2t, 128, 0, wv, cidx, hi, acc);
  #pragma unroll
  for (int et=0;et<4;++et){
    const int g = r0 + et*16 + cidx;
    if (g < N){
      #pragma unroll
      for (int j=0;j<2;++j){
        const int f0 = (wv*2+j)*16 + hi*4;
        f32x4 hv = *(const f32x4*)(h + (size_t)g*Hdim + f0);
        hv += acc[et][j];
        *(f32x4*)(out_h + (size_t)g*Hdim + f0) = hv;
      }
    }
  }
}

__global__ void egcl_init(const float* __restrict__ coord, float* __restrict__ out_coord,
                          int nc, float* __restrict__ zf, int nzf,
                          int* __restrict__ zi, int nzi)
{
  const int i = blockIdx.x*256 + threadIdx.x;
  if (i < nc) out_coord[i] = coord[i];
  if (zf && i < nzf) zf[i] = 0.f;
  if (zi && i < nzi) zi[i] = 0;
}

// all 7 weight transposes in one launch. mode 1: mes1 remap; mode 2: edge1 remap; 0: plain pad.
__global__ void egcl_wconv7(
    const float* s0, const float* s1, const float* s2, const float* s3,
    const float* s4, const float* s5, const float* s6, u16* __restrict__ dst)
{
  static const int kpads[7]  = {288,128,128,160,128,256,128};
  static const int Ks[7]     = {273,128,128,145,128,256,128};
  static const int modes[7]  = {1,0,0,2,0,0,0};
  const int gi = blockIdx.x*256 + threadIdx.x;
  int w = 0, off = 0, boff = 0;
  #pragma unroll
  for (int t=0;t<7;++t){
    const int sz = 128*kpads[t];
    if (gi >= off && gi < off + sz){ w = t; boff = off; }
    off += sz;
  }
  if (gi >= off) return;
  const float* srcs[7] = {s0,s1,s2,s3,s4,s5,s6};
  const int li = gi - boff;
  const int kpad = kpads[w], K = Ks[w], mode = modes[w];
  const int c = li / kpad, k = li - c*kpad;
  int ks;
  if (mode==1)      ks = (k<256) ? k : (k<272 ? k+1 : (k==272 ? 256 : -1));
  else if (mode==2) ks = (k<128) ? k : (k<144 ? k+1 : (k==144 ? 128 : -1));
  else              ks = (k<K) ? k : -1;
  const float v = (ks>=0) ? srcs[w][(size_t)ks*128 + c] : 0.f;
  *(__bf16*)(dst + gi) = (__bf16)v;
}

__global__ void k_hist(const int* __restrict__ ei, int* __restrict__ hist, int E){
  const int i = blockIdx.x*256 + threadIdx.x;
  if (i < E) atomicAdd(&hist[ei[E + i]], 1);
}
__global__ void k_scan1(const int* __restrict__ hist, int* __restrict__ partial, int N){
  __shared__ int s[256];
  const int t = threadIdx.x, i = blockIdx.x*256 + t;
  s[t] = (i < N) ? hist[i] : 0;
  __syncthreads();
  for (int o=128; o>0; o>>=1){ if (t < o) s[t] += s[t+o]; __syncthreads(); }
  if (t == 0) partial[blockIdx.x] = s[0];
}
// parallel exclusive scan of the per-block partials (G<=256; was a single-thread
// serial loop = ~200 dependent global round-trips ~25-35us; fix saved ~12us, r12)
__global__ void k_scan2(int* __restrict__ partial, int G){
  __shared__ int s[256];
  const int t = threadIdx.x;
  if (G <= 256){
    const int v = (t < G) ? partial[t] : 0;
    s[t] = v;
    __syncthreads();
    for (int o=1; o<256; o<<=1){
      int x = (t >= o) ? s[t-o] : 0;
      __syncthreads();
      s[t] += x;
      __syncthreads();
    }
    if (t < G) partial[t] = s[t] - v;   // exclusive
  } else if (t == 0){
    int run = 0;
    for (int i=0;i<G;++i){ const int v = partial[i]; partial[i] = run; run += v; }
  }
}
__global__ void k_scan3(const int* __restrict__ hist, const int* __restrict__ partial,
                        int* __restrict__ offs, int* __restrict__ cursor, int N){
  __shared__ int s[256];
  const int t = threadIdx.x, i = blockIdx.x*256 + t;
  const int v = (i < N) ? hist[i] : 0;
  s[t] = v;
  __syncthreads();
  for (int o=1; o<256; o<<=1){
    int x = (t >= o) ? s[t-o] : 0;
    __syncthreads();
    s[t] += x;
    __syncthreads();
  }
  const int ex = s[t] - v + partial[blockIdx.x];
  if (i < N){ offs[i] = ex; cursor[i] = ex; }
}
__global__ void k_scatter(const int* __restrict__ ei, int* __restrict__ cursor,
                          int* __restrict__ pos, int E){
  const int i = blockIdx.x*256 + threadIdx.x;
  if (i < E){
    const int c = ei[E + i];
    pos[i] = atomicAdd(&cursor[c], 1);
  }
}

extern "C" void kernel_launch(void* const* d_in, const int* in_sizes, int n_in,
                              void* d_out, int out_size, void* d_ws, size_t ws_size,
                              hipStream_t stream)
{
  const float* h       = (const float*)d_in[0];
  const float* coord   = (const float*)d_in[1];
  const int*   ei      = (const int*)d_in[2];
  const float* ea      = (const float*)d_in[3];
  const float* mes_w1  = (const float*)d_in[4];
  const float* mes_b1  = (const float*)d_in[5];
  const float* mes_w2  = (const float*)d_in[6];
  const float* mes_b2  = (const float*)d_in[7];
  const float* edge_w1 = (const float*)d_in[8];
  const float* edge_b1 = (const float*)d_in[9];
  const float* edge_w2 = (const float*)d_in[10];
  const float* edge_b2 = (const float*)d_in[11];
  const float* node_w1 = (const float*)d_in[12];
  const float* node_b1 = (const float*)d_in[13];
  const float* node_w2 = (const float*)d_in[14];
  const float* node_b2 = (const float*)d_in[15];
  const float* coord_w1= (const float*)d_in[16];
  const float* coord_b1= (const float*)d_in[17];
  const float* coord_w2= (const float*)d_in[18];

  const int N = in_sizes[0] / Hdim;
  const int E = in_sizes[2] / 2;
  const int G1 = (N + 255) / 256;

  char* ws = (char*)d_ws;
  const size_t wtot = (size_t)(288+128+128+160+128+256+128)*128;  // u16 elems
  u16* wbase     = (u16*)ws;
  u16* w_mes1t   = wbase;
  u16* w_mes2t   = w_mes1t  + 128*288;
  u16* w_coord1t = w_mes2t  + 128*128;
  u16* w_edge1t  = w_coord1t+ 128*128;
  u16* w_edge2t  = w_edge1t + 128*160;
  u16* w_node1t  = w_edge2t + 128*128;
  u16* w_node2t  = w_node1t + 128*256;

  auto al = [](size_t x){ return (x + 255) & ~(size_t)255; };
  const size_t base   = al(wtot*2);
  const size_t o_feat = base;
  const size_t o_hist = o_feat + al((size_t)E*Hdim*2);
  const size_t o_offs = o_hist + al((size_t)N*4);
  const size_t o_cur  = o_offs + al((size_t)N*4);
  const size_t o_part = o_cur  + al((size_t)N*4);
  const size_t o_pos  = o_part + al((size_t)G1*4);
  const size_t gather_end = o_pos + al((size_t)E*4);
  const size_t o_proj = gather_end;
  const size_t proj_end = o_proj + (size_t)N*256*2;   // bf16 proj table
  const bool gather = (ws_size >= gather_end);
  const bool proj   = (ws_size >= proj_end);

  float* out_h     = (float*)d_out;
  float* out_coord = out_h + (size_t)N*Hdim;
  float* out_edge  = out_coord + (size_t)N*3;

  const int wblocks = (int)((wtot + 255)/256);
  egcl_wconv7<<<wblocks, 256, 0, stream>>>(mes_w1, mes_w2, coord_w1, edge_w1,
                                           edge_w2, node_w1, node_w2, wbase);

  if (gather){
    u16* featb  = (u16*)(ws + o_feat);
    int* hist   = (int*)(ws + o_hist);
    int* offs   = (int*)(ws + o_offs);
    int* cursor = (int*)(ws + o_cur);
    int* partial= (int*)(ws + o_part);
    int* pos    = (int*)(ws + o_pos);
    u16* projp  = (u16*)(ws + o_proj);

    egcl_init<<<(N*3+255)/256, 256, 0, stream>>>(coord, out_coord, N*3, nullptr, 0, hist, N);
    k_hist<<<(E+255)/256, 256, 0, stream>>>(ei, hist, E);
    k_scan1<<<G1, 256, 0, stream>>>(hist, partial, N);
    k_scan2<<<1, 256, 0, stream>>>(partial, G1);
    k_scan3<<<G1, 256, 0, stream>>>(hist, partial, offs, cursor, N);
    k_scatter<<<(E+255)/256, 256, 0, stream>>>(ei, cursor, pos, E);

    if (proj){
      dim3 pg((N+63)/64, 2);
      egcl_proj<<<pg, 256, 0, stream>>>(h, w_mes1t, projp, N);
      egcl_edge<true,true><<<(E+31)/32, 256, 0, stream>>>(h, coord, ei, ea, projp, pos,
          mes_b1, mes_b2, edge_b1, edge_b2, coord_b1, coord_w2,
          w_mes1t, w_mes2t, w_coord1t, w_edge1t, w_edge2t,
          nullptr, featb, out_coord, out_edge, E);
    } else {
      egcl_edge<false,true><<<(E+63)/64, 256, 0, stream>>>(h, coord, ei, ea, nullptr, pos,
          mes_b1, mes_b2, edge_b1, edge_b2, coord_b1, coord_w2,
          w_mes1t, w_mes2t, w_coord1t, w_edge1t, w_edge2t,
          nullptr, featb, out_coord, out_edge, E);
    }
    egcl_node<true><<<(N+63)/64, 256, 0, stream>>>(h, nullptr, offs, hist, featb,
        node_b1, node_b2, w_node1t, w_node2t, out_h, N);
  } else {
    float* agg = (float*)(ws + base);
    egcl_init<<<(N*Hdim+255)/256, 256, 0, stream>>>(coord, out_coord, N*3, agg, N*Hdim, nullptr, 0);
    egcl_edge<false,false><<<(E+63)/64, 256, 0, stream>>>(h, coord, ei, ea, nullptr, nullptr,
        mes_b1, mes_b2, edge_b1, edge_b2, coord_b1, coord_w2,
        w_mes1t, w_mes2t, w_coord1t, w_edge1t, w_edge2t,
        agg, nullptr, out_coord, out_edge, E);
    egcl_node<false><<<(N+63)/64, 256, 0, stream>>>(h, agg, nullptr, nullptr, nullptr,
        node_b1, node_b2, w_node1t, w_node2t, out_h, N);
  }
}

// Round 15
// 618.054 us; speedup vs baseline: 1.1907x; 1.1907x over previous
//
#include <hip/hip_runtime.h>
#include <cstdint>
#include <cstddef>

typedef float f32x4 __attribute__((ext_vector_type(4)));
typedef __bf16 bf16x8 __attribute__((ext_vector_type(8)));
typedef __bf16 bf16x4 __attribute__((ext_vector_type(4)));
typedef unsigned short u16;

#define Hdim 128
#define DEdim 16
#define TP 40          // tail pitch (u16): [ea(16) | radial | zeros..31], 80B rows

__device__ __forceinline__ float bf2f(uint32_t lo16){
  return __builtin_bit_cast(float, lo16 << 16);
}
__device__ __forceinline__ float bfhi(uint32_t v){
  return __builtin_bit_cast(float, v & 0xffff0000u);
}
// fast silu: v_mul, v_exp, v_add, v_rcp, v_mul (avoids IEEE div expansion)
__device__ __forceinline__ float silu_f(float x){
  return x * __builtin_amdgcn_rcpf(1.0f + __expf(-x));
}
__device__ __forceinline__ uint2 pack4(f32x4 v){
  bf16x4 p;
  #pragma unroll
  for (int i=0;i<4;++i) p[i] = (__bf16)v[i];
  return __builtin_bit_cast(uint2, p);
}
__device__ __forceinline__ uint2 silu_pack4(const f32x4& v, f32x4* sout=nullptr){
  f32x4 s;
  #pragma unroll
  for (int i=0;i<4;++i) s[i] = silu_f(v[i]);
  if (sout) *sout = s;
  return pack4(s);
}

// Swapped-operand tile GEMM: OUT[f][e] = W(16f x K) x IN(K x 16e), 4 edge-tiles x 2 feature-tiles.
// arg0 (A-op) = weight frag: lane holds Wt[ftile*16 + (lane&15)][k], k=(lane>>4)*8+slot
// arg1 (B-op) = input frag:  lane holds IN[k][etile*16 + (lane&15)] = LDS[e][k]
// D: reg i -> feature f = ftile*16 + (lane>>4)*4 + i, edge e = etile*16 + (lane&15)
template<int KC>
__device__ __forceinline__ void gemm_sw(
    const u16* A, int apitch,
    const u16* __restrict__ Wt, int kpad, int woff,
    int wv, int cidx, int hi, f32x4 (&acc)[4][2])
{
  const u16* w0p = Wt + (size_t)((wv*2+0)*16 + cidx)*kpad + woff + hi*8;
  const u16* w1p = Wt + (size_t)((wv*2+1)*16 + cidx)*kpad + woff + hi*8;
  const u16* ap  = A + (size_t)cidx*apitch + hi*8;
  #pragma unroll
  for (int kc=0; kc<KC; ++kc){
    bf16x8 w0 = *(const bf16x8*)(w0p + kc*32);
    bf16x8 w1 = *(const bf16x8*)(w1p + kc*32);
    #pragma unroll
    for (int et=0; et<4; ++et){
      bf16x8 a = *(const bf16x8*)(ap + et*16*apitch + kc*32);
      acc[et][0] = __builtin_amdgcn_mfma_f32_16x16x32_bf16(w0, a, acc[et][0], 0,0,0);
      acc[et][1] = __builtin_amdgcn_mfma_f32_16x16x32_bf16(w1, a, acc[et][1], 0,0,0);
    }
  }
}

__device__ __forceinline__ void acc_bias(const float* __restrict__ bias,
                                         int wv, int hi, f32x4 (&acc)[4][2])
{
  f32x4 b0 = *(const f32x4*)(bias + (wv*2+0)*16 + hi*4);
  f32x4 b1 = *(const f32x4*)(bias + (wv*2+1)*16 + hi*4);
  #pragma unroll
  for (int et=0;et<4;++et){ acc[et][0]=b0; acc[et][1]=b1; }
}

template<int SP>
__device__ __forceinline__ void write_silu_S(u16* S, f32x4 (&acc)[4][2],
                                             int wv, int cidx, int hi)
{
  #pragma unroll
  for (int et=0; et<4; ++et){
    const int e = et*16 + cidx;
    #pragma unroll
    for (int j=0;j<2;++j){
      const int f0 = (wv*2+j)*16 + hi*4;
      *(uint2*)(S + (size_t)e*SP + f0) = silu_pack4(acc[et][j]);
    }
  }
}

// CONVERGED STATE (r13, verified twice at 619us total / 445us edge):
// ET=4 tile, 4 waves/SIMD, 6 barriers, single-S. Exhaustive local search:
// - bigger tile ET=8 -> spill (r8); smaller ET=2 -> weight-reuse loss +30% (r14)
// - occupancy 5/6 w/SIMD -> spill (r7/r10); LDS dbuf -> spill (r12)
// - barrier-free per-wave -> 4x weight traffic (r5)
// True live state ~110-125 unified VGPR+AGPR; only the 128-reg tier fits.
template<bool PROJ, bool GATHER>
__global__ __launch_bounds__(256, PROJ?4:3) void egcl_edge(
    const float* __restrict__ h, const float* __restrict__ coord,
    const int* __restrict__ ei, const float* __restrict__ ea,
    const u16* __restrict__ projf, const int* __restrict__ pos,
    const float* __restrict__ mes_b1, const float* __restrict__ mes_b2,
    const float* __restrict__ edge_b1, const float* __restrict__ edge_b2,
    const float* __restrict__ coord_b1, const float* __restrict__ coord_w2,
    const u16* __restrict__ w_mes1t, const u16* __restrict__ w_mes2t,
    const u16* __restrict__ w_coord1t, const u16* __restrict__ w_edge1t,
    const u16* __restrict__ w_edge2t,
    float* __restrict__ agg, u16* __restrict__ featb,
    float* __restrict__ out_coord, float* __restrict__ out_edge, int E)
{
  constexpr int SP = PROJ ? 136 : 264;   // 272B / 528B rows: conflict-free b128
  __shared__ u16 S[64*SP];
  __shared__ u16 T[64*TP];
  __shared__ float cds[64*4];
  __shared__ float tvs[4][64];
  __shared__ int cnode[64];

  const int tid  = threadIdx.x;
  const int lane = tid & 63;
  const int wv   = tid >> 6;
  const int e0   = blockIdx.x * 64;
  const int cidx = lane & 15;
  const int hi   = lane >> 4;

  // ---------- early-issued proj gathers (bf16): latency overlaps stage+B1 ----------
  ushort4 gr[4][2], gc[4][2];
  if constexpr (PROJ){
    #pragma unroll
    for (int et=0;et<4;++et){
      int eg = e0 + et*16 + cidx; if (eg >= E) eg = E-1;
      const int rn = ei[eg], cn = ei[E + eg];
      const u16* pr = projf + (size_t)rn*256 + wv*32 + hi*4;
      const u16* pc = projf + (size_t)cn*256 + 128 + wv*32 + hi*4;
      gr[et][0] = *(const ushort4*)(pr);
      gr[et][1] = *(const ushort4*)(pr + 16);
      gc[et][0] = *(const ushort4*)(pc);
      gc[et][1] = *(const ushort4*)(pc + 16);
    }
  }

  // ---------- stage ----------
  {
    const int le   = wv*16 + (lane>>2);
    const int part = lane & 3;
    int eg = e0 + le; if (eg >= E) eg = E-1;
    if constexpr (!PROJ){
      const int rn = ei[eg], cn = ei[E + eg];
      // S[e][0..128) = h[rn] bf16, [128..256) = h[cn]
      const float* src = ((part<2) ? h + (size_t)rn*Hdim : h + (size_t)cn*Hdim) + (part&1)*64;
      u16* dst = S + (size_t)le*SP + part*64;
      #pragma unroll
      for (int q=0;q<16;++q){
        float4 v = ((const float4*)src)[q];
        bf16x4 o = {(__bf16)v.x,(__bf16)v.y,(__bf16)v.z,(__bf16)v.w};
        *(bf16x4*)(dst + q*4) = o;
      }
    }
    if (part == 0){
      const int rn = ei[eg], cn = ei[E + eg];
      cnode[le] = cn;
      const float dx = coord[(size_t)rn*3+0] - coord[(size_t)cn*3+0];
      const float dy = coord[(size_t)rn*3+1] - coord[(size_t)cn*3+1];
      const float dz = coord[(size_t)rn*3+2] - coord[(size_t)cn*3+2];
      const float radial = dx*dx + dy*dy + dz*dz;
      const float inv = __builtin_amdgcn_rcpf(sqrtf(radial + 1e-8f) + 1.0f);
      cds[le*4+0]=dx*inv; cds[le*4+1]=dy*inv; cds[le*4+2]=dz*inv; cds[le*4+3]=radial;
      u16* tp = T + le*TP;
      const float4* eap = (const float4*)(ea + (size_t)eg*DEdim);
      #pragma unroll
      for (int q=0;q<4;++q){
        float4 v = eap[q];
        bf16x4 o = {(__bf16)v.x,(__bf16)v.y,(__bf16)v.z,(__bf16)v.w};
        *(bf16x4*)(tp + q*4) = o;
      }
      bf16x4 z = {(__bf16)0.f,(__bf16)0.f,(__bf16)0.f,(__bf16)0.f};
      *(bf16x4*)(tp+16) = z; *(bf16x4*)(tp+20) = z;
      *(bf16x4*)(tp+24) = z; *(bf16x4*)(tp+28) = z;
      *(__bf16*)(tp+16) = (__bf16)radial;       // T col16 = radial (after zeros)
    }
  }
  __syncthreads();                                   // B1

  f32x4 acc[4][2];

  // ---------- mes layer 1 ----------
  acc_bias(mes_b1, wv, hi, acc);
  if constexpr (PROJ){
    #pragma unroll
    for (int et=0;et<4;++et){
      #pragma unroll
      for (int j=0;j<2;++j){
        acc[et][j][0] += bf2f(gr[et][j].x) + bf2f(gc[et][j].x);
        acc[et][j][1] += bf2f(gr[et][j].y) + bf2f(gc[et][j].y);
        acc[et][j][2] += bf2f(gr[et][j].z) + bf2f(gc[et][j].z);
        acc[et][j][3] += bf2f(gr[et][j].w) + bf2f(gc[et][j].w);
      }
    }
    gemm_sw<1>(T, TP, w_mes1t, 288, 256, wv, cidx, hi, acc);
  } else {
    gemm_sw<8>(S, SP, w_mes1t, 288, 0,   wv, cidx, hi, acc);
    gemm_sw<1>(T, TP, w_mes1t, 288, 256, wv, cidx, hi, acc);
    __syncthreads();   // S K-reads done before overwriting cols [0,128)
  }
  write_silu_S<SP>(S, acc, wv, cidx, hi);
  __syncthreads();                                   // B2

  // ---------- mes layer 2 -> edge_feat ----------
  acc_bias(mes_b2, wv, hi, acc);
  gemm_sw<4>(S, SP, w_mes2t, 128, 0, wv, cidx, hi, acc);
  uint2 ps[4][2];
  #pragma unroll
  for (int et=0;et<4;++et)
    #pragma unroll
    for (int j=0;j<2;++j){
      f32x4 sv;
      ps[et][j] = silu_pack4(acc[et][j], &sv);
      if constexpr (!GATHER){
        const int e = et*16 + cidx;
        if (e0 + e < E){
          const int f0 = (wv*2+j)*16 + hi*4;
          #pragma unroll
          for (int i=0;i<4;++i)
            atomicAdd(agg + (size_t)cnode[e]*Hdim + f0 + i, sv[i]);
        }
      }
    }
  __syncthreads();                                   // B3 (S K-reads done)
  #pragma unroll
  for (int et=0;et<4;++et)
    #pragma unroll
    for (int j=0;j<2;++j)
      *(uint2*)(S + (size_t)(et*16+cidx)*SP + (wv*2+j)*16 + hi*4) = ps[et][j];
  __syncthreads();                                   // B4

  if constexpr (GATHER){
    // stream feat row to its CSR slot: fully coalesced 64B/4-lane-group
    const int row = tid >> 2, seg = tid & 3;
    if (e0 + row < E){
      const int4* s = (const int4*)(S + (size_t)row*SP + seg*32);
      int4* d = (int4*)(featb + (size_t)pos[e0+row]*Hdim + seg*32);
      d[0]=s[0]; d[1]=s[1]; d[2]=s[2]; d[3]=s[3];
    }
  }

  // ---------- coord layer ----------
  acc_bias(coord_b1, wv, hi, acc);
  gemm_sw<4>(S, SP, w_coord1t, 128, 0, wv, cidx, hi, acc);
  {
    f32x4 cw0 = *(const f32x4*)(coord_w2 + (wv*2+0)*16 + hi*4);
    f32x4 cw1 = *(const f32x4*)(coord_w2 + (wv*2+1)*16 + hi*4);
    #pragma unroll
    for (int et=0;et<4;++et){
      float p = 0.f;
      #pragma unroll
      for (int i=0;i<4;++i)
        p += silu_f(acc[et][0][i])*cw0[i] + silu_f(acc[et][1][i])*cw1[i];
      p += __shfl_xor(p, 16);
      p += __shfl_xor(p, 32);
      if (hi == 0) tvs[wv][et*16+cidx] = p;
    }
  }

  // ---------- edge layer 1 ----------
  acc_bias(edge_b1, wv, hi, acc);
  gemm_sw<4>(S, SP, w_edge1t, 160, 0,   wv, cidx, hi, acc);
  gemm_sw<1>(T, TP, w_edge1t, 160, 128, wv, cidx, hi, acc);
  #pragma unroll
  for (int et=0;et<4;++et)
    #pragma unroll
    for (int j=0;j<2;++j)
      ps[et][j] = silu_pack4(acc[et][j]);
  __syncthreads();                                   // B5 (tvs ready; S K-reads done)
  #pragma unroll
  for (int et=0;et<4;++et)
    #pragma unroll
    for (int j=0;j<2;++j)
      *(uint2*)(S + (size_t)(et*16+cidx)*SP + (wv*2+j)*16 + hi*4) = ps[et][j];
  __syncthreads();                                   // B6

  // ---------- edge layer 2 (no activation) ----------
  acc_bias(edge_b2, wv, hi, acc);
  gemm_sw<4>(S, SP, w_edge2t, 128, 0, wv, cidx, hi, acc);
  #pragma unroll
  for (int et=0;et<4;++et){
    const int e = e0 + et*16 + cidx;
    if (e < E){
      #pragma unroll
      for (int j=0;j<2;++j)
        *(f32x4*)(out_edge + (size_t)e*Hdim + (wv*2+j)*16 + hi*4) = acc[et][j];
    }
  }

  // ---------- coord scatter (after last barrier: contended-atomic drain
  // overlaps block teardown instead of sitting inside the barrier chain) ----------
  if (tid < 192){
    const int le = tid/3, d = tid - le*3;
    if (e0 + le < E){
      const float t4 = tvs[0][le]+tvs[1][le]+tvs[2][le]+tvs[3][le];
      atomicAdd(out_coord + (size_t)cnode[le]*3 + d, cds[le*4+d]*t4);
    }
  }
}

// proj[n][half*128+f] = sum_k h[n][k] * mes_w1[half*128+k][f]   (bf16 out)
__global__ __launch_bounds__(256, 4) void egcl_proj(
    const float* __restrict__ h, const u16* __restrict__ w_mes1t,
    u16* __restrict__ proj, int N)
{
  __shared__ u16 S[64*136];
  const int tid=threadIdx.x, lane=tid&63, wv=tid>>6, cidx=lane&15, hi=lane>>4;
  const int r0 = blockIdx.x*64, half = blockIdx.y;
  {
    const int le = tid>>2, part = tid&3;
    int g = r0 + le; if (g >= N) g = N-1;
    const float* src = h + (size_t)g*Hdim + part*32;
    u16* dst = S + (size_t)le*136 + part*32;
    #pragma unroll
    for (int q=0;q<8;++q){
      float4 v = ((const float4*)src)[q];
      bf16x4 o = {(__bf16)v.x,(__bf16)v.y,(__bf16)v.z,(__bf16)v.w};
      *(bf16x4*)(dst + q*4) = o;
    }
  }
  __syncthreads();
  f32x4 acc[4][2];
  #pragma unroll
  for (int et=0;et<4;++et){ acc[et][0]=(f32x4){0,0,0,0}; acc[et][1]=(f32x4){0,0,0,0}; }
  gemm_sw<4>(S, 136, w_mes1t, 288, half*128, wv, cidx, hi, acc);
  #pragma unroll
  for (int et=0;et<4;++et){
    const int g = r0 + et*16 + cidx;
    if (g < N){
      #pragma unroll
      for (int j=0;j<2;++j)
        *(uint2*)(proj + (size_t)g*256 + half*128 + (wv*2+j)*16 + hi*4) = pack4(acc[et][j]);
    }
  }
}

template<bool GATHER>
__global__ __launch_bounds__(256, 4) void egcl_node(
    const float* __restrict__ h, const float* __restrict__ agg,
    const int* __restrict__ offs, const int* __restrict__ deg,
    const u16* __restrict__ featb,
    const float* __restrict__ node_b1, const float* __restrict__ node_b2,
    const u16* __restrict__ w_node1t, const u16* __restrict__ w_node2t,
    float* __restrict__ out_h, int N)
{
  __shared__ u16 Ab[64*264];
  const int tid=threadIdx.x, lane=tid&63, wv=tid>>6, cidx=lane&15, hi=lane>>4;
  const int r0 = blockIdx.x*64;
  // stage h -> cols [0,128)
  {
    const int le = tid>>2, part = tid&3;
    int g = r0 + le; if (g >= N) g = N-1;
    const float* src = h + (size_t)g*Hdim + part*32;
    u16* dst = Ab + (size_t)le*264 + part*32;
    #pragma unroll
    for (int q=0;q<8;++q){
      float4 v = ((const float4*)src)[q];
      bf16x4 o = {(__bf16)v.x,(__bf16)v.y,(__bf16)v.z,(__bf16)v.w};
      *(bf16x4*)(dst + q*4) = o;
    }
  }
  // agg -> cols [128,256)
  if constexpr (GATHER){
    const int le = tid>>2, part = tid&3;
    const int g = r0 + le;
    float a[32];
    #pragma unroll
    for (int q=0;q<32;++q) a[q]=0.f;
    if (g < N){
      const int s = offs[g], dg = deg[g];
      const u16* base = featb + (size_t)s*Hdim + part*32;
      #pragma unroll 2
      for (int r=0;r<dg;++r){
        const uint4* rp = (const uint4*)(base + (size_t)r*Hdim);
        #pragma unroll
        for (int q=0;q<4;++q){
          uint4 w = rp[q];
          a[q*8+0] += bf2f(w.x & 0xffffu); a[q*8+1] += bfhi(w.x);
          a[q*8+2] += bf2f(w.y & 0xffffu); a[q*8+3] += bfhi(w.y);
          a[q*8+4] += bf2f(w.z & 0xffffu); a[q*8+5] += bfhi(w.z);
          a[q*8+6] += bf2f(w.w & 0xffffu); a[q*8+7] += bfhi(w.w);
        }
      }
    }
    u16* dst = Ab + (size_t)le*264 + 128 + part*32;
    #pragma unroll
    for (int q=0;q<8;++q){
      bf16x4 o = {(__bf16)a[q*4+0],(__bf16)a[q*4+1],(__bf16)a[q*4+2],(__bf16)a[q*4+3]};
      *(bf16x4*)(dst + q*4) = o;
    }
  } else {
    const int le = tid>>2, part = tid&3;
    int g = r0 + le; if (g >= N) g = N-1;
    const float* src = agg + (size_t)g*Hdim + part*32;
    u16* dst = Ab + (size_t)le*264 + 128 + part*32;
    #pragma unroll
    for (int q=0;q<8;++q){
      float4 v = ((const float4*)src)[q];
      bf16x4 o = {(__bf16)v.x,(__bf16)v.y,(__bf16)v.z,(__bf16)v.w};
      *(bf16x4*)(dst + q*4) = o;
    }
  }
  __syncthreads();

  f32x4 acc[4][2];
  acc_bias(node_b1, wv, hi, acc);
  gemm_sw<8>(Ab, 264, w_node1t, 256, 0, wv, cidx, hi, acc);
  __syncthreads();
  write_silu_S<264>(Ab, acc, wv, cidx, hi);
  __syncthreads();
  acc_bias(node_b2, wv, hi, acc);
  gemm_sw<4>(Ab, 264, w_node2t, 128, 0, wv, cidx, hi, acc);
  #pragma unroll
  for (int et=0;et<4;++et){
    const int g = r0 + et*16 + cidx;
    if (g < N){
      #pragma unroll
      for (int j=0;j<2;++j){
        const int f0 = (wv*2+j)*16 + hi*4;
        f32x4 hv = *(const f32x4*)(h + (size_t)g*Hdim + f0);
        hv += acc[et][j];
        *(f32x4*)(out_h + (size_t)g*Hdim + f0) = hv;
      }
    }
  }
}

__global__ void egcl_init(const float* __restrict__ coord, float* __restrict__ out_coord,
                          int nc, float* __restrict__ zf, int nzf,
                          int* __restrict__ zi, int nzi)
{
  const int i = blockIdx.x*256 + threadIdx.x;
  if (i < nc) out_coord[i] = coord[i];
  if (zf && i < nzf) zf[i] = 0.f;
  if (zi && i < nzi) zi[i] = 0;
}

// all 7 weight transposes in one launch. mode 1: mes1 remap; mode 2: edge1 remap; 0: plain pad.
__global__ void egcl_wconv7(
    const float* s0, const float* s1, const float* s2, const float* s3,
    const float* s4, const float* s5, const float* s6, u16* __restrict__ dst)
{
  static const int kpads[7]  = {288,128,128,160,128,256,128};
  static const int Ks[7]     = {273,128,128,145,128,256,128};
  static const int modes[7]  = {1,0,0,2,0,0,0};
  const int gi = blockIdx.x*256 + threadIdx.x;
  int w = 0, off = 0, boff = 0;
  #pragma unroll
  for (int t=0;t<7;++t){
    const int sz = 128*kpads[t];
    if (gi >= off && gi < off + sz){ w = t; boff = off; }
    off += sz;
  }
  if (gi >= off) return;
  const float* srcs[7] = {s0,s1,s2,s3,s4,s5,s6};
  const int li = gi - boff;
  const int kpad = kpads[w], K = Ks[w], mode = modes[w];
  const int c = li / kpad, k = li - c*kpad;
  int ks;
  if (mode==1)      ks = (k<256) ? k : (k<272 ? k+1 : (k==272 ? 256 : -1));
  else if (mode==2) ks = (k<128) ? k : (k<144 ? k+1 : (k==144 ? 128 : -1));
  else              ks = (k<K) ? k : -1;
  const float v = (ks>=0) ? srcs[w][(size_t)ks*128 + c] : 0.f;
  *(__bf16*)(dst + gi) = (__bf16)v;
}

__global__ void k_hist(const int* __restrict__ ei, int* __restrict__ hist, int E){
  const int i = blockIdx.x*256 + threadIdx.x;
  if (i < E) atomicAdd(&hist[ei[E + i]], 1);
}
__global__ void k_scan1(const int* __restrict__ hist, int* __restrict__ partial, int N){
  __shared__ int s[256];
  const int t = threadIdx.x, i = blockIdx.x*256 + t;
  s[t] = (i < N) ? hist[i] : 0;
  __syncthreads();
  for (int o=128; o>0; o>>=1){ if (t < o) s[t] += s[t+o]; __syncthreads(); }
  if (t == 0) partial[blockIdx.x] = s[0];
}
// parallel exclusive scan of the per-block partials (G<=256; was a single-thread
// serial loop = ~200 dependent global round-trips ~25-35us; fix saved ~12us, r12)
__global__ void k_scan2(int* __restrict__ partial, int G){
  __shared__ int s[256];
  const int t = threadIdx.x;
  if (G <= 256){
    const int v = (t < G) ? partial[t] : 0;
    s[t] = v;
    __syncthreads();
    for (int o=1; o<256; o<<=1){
      int x = (t >= o) ? s[t-o] : 0;
      __syncthreads();
      s[t] += x;
      __syncthreads();
    }
    if (t < G) partial[t] = s[t] - v;   // exclusive
  } else if (t == 0){
    int run = 0;
    for (int i=0;i<G;++i){ const int v = partial[i]; partial[i] = run; run += v; }
  }
}
__global__ void k_scan3(const int* __restrict__ hist, const int* __restrict__ partial,
                        int* __restrict__ offs, int* __restrict__ cursor, int N){
  __shared__ int s[256];
  const int t = threadIdx.x, i = blockIdx.x*256 + t;
  const int v = (i < N) ? hist[i] : 0;
  s[t] = v;
  __syncthreads();
  for (int o=1; o<256; o<<=1){
    int x = (t >= o) ? s[t-o] : 0;
    __syncthreads();
    s[t] += x;
    __syncthreads();
  }
  const int ex = s[t] - v + partial[blockIdx.x];
  if (i < N){ offs[i] = ex; cursor[i] = ex; }
}
__global__ void k_scatter(const int* __restrict__ ei, int* __restrict__ cursor,
                          int* __restrict__ pos, int E){
  const int i = blockIdx.x*256 + threadIdx.x;
  if (i < E){
    const int c = ei[E + i];
    pos[i] = atomicAdd(&cursor[c], 1);
  }
}

extern "C" void kernel_launch(void* const* d_in, const int* in_sizes, int n_in,
                              void* d_out, int out_size, void* d_ws, size_t ws_size,
                              hipStream_t stream)
{
  const float* h       = (const float*)d_in[0];
  const float* coord   = (const float*)d_in[1];
  const int*   ei      = (const int*)d_in[2];
  const float* ea      = (const float*)d_in[3];
  const float* mes_w1  = (const float*)d_in[4];
  const float* mes_b1  = (const float*)d_in[5];
  const float* mes_w2  = (const float*)d_in[6];
  const float* mes_b2  = (const float*)d_in[7];
  const float* edge_w1 = (const float*)d_in[8];
  const float* edge_b1 = (const float*)d_in[9];
  const float* edge_w2 = (const float*)d_in[10];
  const float* edge_b2 = (const float*)d_in[11];
  const float* node_w1 = (const float*)d_in[12];
  const float* node_b1 = (const float*)d_in[13];
  const float* node_w2 = (const float*)d_in[14];
  const float* node_b2 = (const float*)d_in[15];
  const float* coord_w1= (const float*)d_in[16];
  const float* coord_b1= (const float*)d_in[17];
  const float* coord_w2= (const float*)d_in[18];

  const int N = in_sizes[0] / Hdim;
  const int E = in_sizes[2] / 2;
  const int G1 = (N + 255) / 256;

  char* ws = (char*)d_ws;
  const size_t wtot = (size_t)(288+128+128+160+128+256+128)*128;  // u16 elems
  u16* wbase     = (u16*)ws;
  u16* w_mes1t   = wbase;
  u16* w_mes2t   = w_mes1t  + 128*288;
  u16* w_coord1t = w_mes2t  + 128*128;
  u16* w_edge1t  = w_coord1t+ 128*128;
  u16* w_edge2t  = w_edge1t + 128*160;
  u16* w_node1t  = w_edge2t + 128*128;
  u16* w_node2t  = w_node1t + 128*256;

  auto al = [](size_t x){ return (x + 255) & ~(size_t)255; };
  const size_t base   = al(wtot*2);
  const size_t o_feat = base;
  const size_t o_hist = o_feat + al((size_t)E*Hdim*2);
  const size_t o_offs = o_hist + al((size_t)N*4);
  const size_t o_cur  = o_offs + al((size_t)N*4);
  const size_t o_part = o_cur  + al((size_t)N*4);
  const size_t o_pos  = o_part + al((size_t)G1*4);
  const size_t gather_end = o_pos + al((size_t)E*4);
  const size_t o_proj = gather_end;
  const size_t proj_end = o_proj + (size_t)N*256*2;   // bf16 proj table
  const bool gather = (ws_size >= gather_end);
  const bool proj   = (ws_size >= proj_end);

  float* out_h     = (float*)d_out;
  float* out_coord = out_h + (size_t)N*Hdim;
  float* out_edge  = out_coord + (size_t)N*3;

  const int wblocks = (int)((wtot + 255)/256);
  egcl_wconv7<<<wblocks, 256, 0, stream>>>(mes_w1, mes_w2, coord_w1, edge_w1,
                                           edge_w2, node_w1, node_w2, wbase);

  if (gather){
    u16* featb  = (u16*)(ws + o_feat);
    int* hist   = (int*)(ws + o_hist);
    int* offs   = (int*)(ws + o_offs);
    int* cursor = (int*)(ws + o_cur);
    int* partial= (int*)(ws + o_part);
    int* pos    = (int*)(ws + o_pos);
    u16* projp  = (u16*)(ws + o_proj);

    egcl_init<<<(N*3+255)/256, 256, 0, stream>>>(coord, out_coord, N*3, nullptr, 0, hist, N);
    k_hist<<<(E+255)/256, 256, 0, stream>>>(ei, hist, E);
    k_scan1<<<G1, 256, 0, stream>>>(hist, partial, N);
    k_scan2<<<1, 256, 0, stream>>>(partial, G1);
    k_scan3<<<G1, 256, 0, stream>>>(hist, partial, offs, cursor, N);
    k_scatter<<<(E+255)/256, 256, 0, stream>>>(ei, cursor, pos, E);

    if (proj){
      dim3 pg((N+63)/64, 2);
      egcl_proj<<<pg, 256, 0, stream>>>(h, w_mes1t, projp, N);
      egcl_edge<true,true><<<(E+63)/64, 256, 0, stream>>>(h, coord, ei, ea, projp, pos,
          mes_b1, mes_b2, edge_b1, edge_b2, coord_b1, coord_w2,
          w_mes1t, w_mes2t, w_coord1t, w_edge1t, w_edge2t,
          nullptr, featb, out_coord, out_edge, E);
    } else {
      egcl_edge<false,true><<<(E+63)/64, 256, 0, stream>>>(h, coord, ei, ea, nullptr, pos,
          mes_b1, mes_b2, edge_b1, edge_b2, coord_b1, coord_w2,
          w_mes1t, w_mes2t, w_coord1t, w_edge1t, w_edge2t,
          nullptr, featb, out_coord, out_edge, E);
    }
    egcl_node<true><<<(N+63)/64, 256, 0, stream>>>(h, nullptr, offs, hist, featb,
        node_b1, node_b2, w_node1t, w_node2t, out_h, N);
  } else {
    float* agg = (float*)(ws + base);
    egcl_init<<<(N*Hdim+255)/256, 256, 0, stream>>>(coord, out_coord, N*3, agg, N*Hdim, nullptr, 0);
    egcl_edge<false,false><<<(E+63)/64, 256, 0, stream>>>(h, coord, ei, ea, nullptr, nullptr,
        mes_b1, mes_b2, edge_b1, edge_b2, coord_b1, coord_w2,
        w_mes1t, w_mes2t, w_coord1t, w_edge1t, w_edge2t,
        agg, nullptr, out_coord, out_edge, E);
    egcl_node<false><<<(N+63)/64, 256, 0, stream>>>(h, agg, nullptr, nullptr, nullptr,
        node_b1, node_b2, w_node1t, w_node2t, out_h, N);
  }
}

// Round 16
// 617.940 us; speedup vs baseline: 1.1909x; 1.0002x over previous
//
#include <hip/hip_runtime.h>
#include <cstdint>
#include <cstddef>

typedef float f32x4 __attribute__((ext_vector_type(4)));
typedef __bf16 bf16x8 __attribute__((ext_vector_type(8)));
typedef __bf16 bf16x4 __attribute__((ext_vector_type(4)));
typedef unsigned short u16;

#define Hdim 128
#define DEdim 16
#define TP 40          // tail pitch (u16): [ea(16) | radial | zeros..31], 80B rows

__device__ __forceinline__ float bf2f(uint32_t lo16){
  return __builtin_bit_cast(float, lo16 << 16);
}
__device__ __forceinline__ float bfhi(uint32_t v){
  return __builtin_bit_cast(float, v & 0xffff0000u);
}
// fast silu: v_mul, v_exp, v_add, v_rcp, v_mul (avoids IEEE div expansion)
__device__ __forceinline__ float silu_f(float x){
  return x * __builtin_amdgcn_rcpf(1.0f + __expf(-x));
}
__device__ __forceinline__ uint2 pack4(f32x4 v){
  bf16x4 p;
  #pragma unroll
  for (int i=0;i<4;++i) p[i] = (__bf16)v[i];
  return __builtin_bit_cast(uint2, p);
}
__device__ __forceinline__ uint2 silu_pack4(const f32x4& v, f32x4* sout=nullptr){
  f32x4 s;
  #pragma unroll
  for (int i=0;i<4;++i) s[i] = silu_f(v[i]);
  if (sout) *sout = s;
  return pack4(s);
}

// Swapped-operand tile GEMM: OUT[f][e] = W(16f x K) x IN(K x 16e), 4 edge-tiles x 2 feature-tiles.
// arg0 (A-op) = weight frag: lane holds Wt[ftile*16 + (lane&15)][k], k=(lane>>4)*8+slot
// arg1 (B-op) = input frag:  lane holds IN[k][etile*16 + (lane&15)] = LDS[e][k]
// D: reg i -> feature f = ftile*16 + (lane>>4)*4 + i, edge e = etile*16 + (lane&15)
template<int KC>
__device__ __forceinline__ void gemm_sw(
    const u16* A, int apitch,
    const u16* __restrict__ Wt, int kpad, int woff,
    int wv, int cidx, int hi, f32x4 (&acc)[4][2])
{
  const u16* w0p = Wt + (size_t)((wv*2+0)*16 + cidx)*kpad + woff + hi*8;
  const u16* w1p = Wt + (size_t)((wv*2+1)*16 + cidx)*kpad + woff + hi*8;
  const u16* ap  = A + (size_t)cidx*apitch + hi*8;
  #pragma unroll
  for (int kc=0; kc<KC; ++kc){
    bf16x8 w0 = *(const bf16x8*)(w0p + kc*32);
    bf16x8 w1 = *(const bf16x8*)(w1p + kc*32);
    #pragma unroll
    for (int et=0; et<4; ++et){
      bf16x8 a = *(const bf16x8*)(ap + et*16*apitch + kc*32);
      acc[et][0] = __builtin_amdgcn_mfma_f32_16x16x32_bf16(w0, a, acc[et][0], 0,0,0);
      acc[et][1] = __builtin_amdgcn_mfma_f32_16x16x32_bf16(w1, a, acc[et][1], 0,0,0);
    }
  }
}

__device__ __forceinline__ void acc_bias(const float* __restrict__ bias,
                                         int wv, int hi, f32x4 (&acc)[4][2])
{
  f32x4 b0 = *(const f32x4*)(bias + (wv*2+0)*16 + hi*4);
  f32x4 b1 = *(const f32x4*)(bias + (wv*2+1)*16 + hi*4);
  #pragma unroll
  for (int et=0;et<4;++et){ acc[et][0]=b0; acc[et][1]=b1; }
}

template<int SP>
__device__ __forceinline__ void write_silu_S(u16* S, f32x4 (&acc)[4][2],
                                             int wv, int cidx, int hi)
{
  #pragma unroll
  for (int et=0; et<4; ++et){
    const int e = et*16 + cidx;
    #pragma unroll
    for (int j=0;j<2;++j){
      const int f0 = (wv*2+j)*16 + hi*4;
      *(uint2*)(S + (size_t)e*SP + f0) = silu_pack4(acc[et][j]);
    }
  }
}

// CONVERGED STATE (r13/r15, verified 3x at 618-619us total / 445us edge):
// ET=4 tile, 4 waves/SIMD, 6 barriers, single-S. Exhaustive local search:
// - bigger tile ET=8 -> spill (r8); smaller ET=2 -> weight-reuse loss +30% (r14)
// - occupancy 5/6 w/SIMD -> spill (r7/r10); LDS dbuf -> spill (r12)
// - barrier-free per-wave -> 4x weight traffic (r5)
// True live state ~110-125 unified VGPR+AGPR; only the 128-reg tier fits.
template<bool PROJ, bool GATHER>
__global__ __launch_bounds__(256, PROJ?4:3) void egcl_edge(
    const float* __restrict__ h, const float* __restrict__ coord,
    const int* __restrict__ ei, const float* __restrict__ ea,
    const u16* __restrict__ projf, const int* __restrict__ pos,
    const float* __restrict__ mes_b1, const float* __restrict__ mes_b2,
    const float* __restrict__ edge_b1, const float* __restrict__ edge_b2,
    const float* __restrict__ coord_b1, const float* __restrict__ coord_w2,
    const u16* __restrict__ w_mes1t, const u16* __restrict__ w_mes2t,
    const u16* __restrict__ w_coord1t, const u16* __restrict__ w_edge1t,
    const u16* __restrict__ w_edge2t,
    float* __restrict__ agg, u16* __restrict__ featb,
    float* __restrict__ out_coord, float* __restrict__ out_edge, int E)
{
  constexpr int SP = PROJ ? 136 : 264;   // 272B / 528B rows: conflict-free b128
  __shared__ u16 S[64*SP];
  __shared__ u16 T[64*TP];
  __shared__ float cds[64*4];
  __shared__ float tvs[4][64];
  __shared__ int cnode[64];

  const int tid  = threadIdx.x;
  const int lane = tid & 63;
  const int wv   = tid >> 6;
  const int e0   = blockIdx.x * 64;
  const int cidx = lane & 15;
  const int hi   = lane >> 4;

  // ---------- early-issued proj gathers (bf16): latency overlaps stage+B1 ----------
  ushort4 gr[4][2], gc[4][2];
  if constexpr (PROJ){
    #pragma unroll
    for (int et=0;et<4;++et){
      int eg = e0 + et*16 + cidx; if (eg >= E) eg = E-1;
      const int rn = ei[eg], cn = ei[E + eg];
      const u16* pr = projf + (size_t)rn*256 + wv*32 + hi*4;
      const u16* pc = projf + (size_t)cn*256 + 128 + wv*32 + hi*4;
      gr[et][0] = *(const ushort4*)(pr);
      gr[et][1] = *(const ushort4*)(pr + 16);
      gc[et][0] = *(const ushort4*)(pc);
      gc[et][1] = *(const ushort4*)(pc + 16);
    }
  }

  // ---------- stage ----------
  {
    const int le   = wv*16 + (lane>>2);
    const int part = lane & 3;
    int eg = e0 + le; if (eg >= E) eg = E-1;
    if constexpr (!PROJ){
      const int rn = ei[eg], cn = ei[E + eg];
      // S[e][0..128) = h[rn] bf16, [128..256) = h[cn]
      const float* src = ((part<2) ? h + (size_t)rn*Hdim : h + (size_t)cn*Hdim) + (part&1)*64;
      u16* dst = S + (size_t)le*SP + part*64;
      #pragma unroll
      for (int q=0;q<16;++q){
        float4 v = ((const float4*)src)[q];
        bf16x4 o = {(__bf16)v.x,(__bf16)v.y,(__bf16)v.z,(__bf16)v.w};
        *(bf16x4*)(dst + q*4) = o;
      }
    }
    if (part == 0){
      const int rn = ei[eg], cn = ei[E + eg];
      cnode[le] = cn;
      const float dx = coord[(size_t)rn*3+0] - coord[(size_t)cn*3+0];
      const float dy = coord[(size_t)rn*3+1] - coord[(size_t)cn*3+1];
      const float dz = coord[(size_t)rn*3+2] - coord[(size_t)cn*3+2];
      const float radial = dx*dx + dy*dy + dz*dz;
      const float inv = __builtin_amdgcn_rcpf(sqrtf(radial + 1e-8f) + 1.0f);
      cds[le*4+0]=dx*inv; cds[le*4+1]=dy*inv; cds[le*4+2]=dz*inv; cds[le*4+3]=radial;
      u16* tp = T + le*TP;
      const float4* eap = (const float4*)(ea + (size_t)eg*DEdim);
      #pragma unroll
      for (int q=0;q<4;++q){
        float4 v = eap[q];
        bf16x4 o = {(__bf16)v.x,(__bf16)v.y,(__bf16)v.z,(__bf16)v.w};
        *(bf16x4*)(tp + q*4) = o;
      }
      bf16x4 z = {(__bf16)0.f,(__bf16)0.f,(__bf16)0.f,(__bf16)0.f};
      *(bf16x4*)(tp+16) = z; *(bf16x4*)(tp+20) = z;
      *(bf16x4*)(tp+24) = z; *(bf16x4*)(tp+28) = z;
      *(__bf16*)(tp+16) = (__bf16)radial;       // T col16 = radial (after zeros)
    }
  }
  __syncthreads();                                   // B1

  f32x4 acc[4][2];

  // ---------- mes layer 1 ----------
  acc_bias(mes_b1, wv, hi, acc);
  if constexpr (PROJ){
    #pragma unroll
    for (int et=0;et<4;++et){
      #pragma unroll
      for (int j=0;j<2;++j){
        acc[et][j][0] += bf2f(gr[et][j].x) + bf2f(gc[et][j].x);
        acc[et][j][1] += bf2f(gr[et][j].y) + bf2f(gc[et][j].y);
        acc[et][j][2] += bf2f(gr[et][j].z) + bf2f(gc[et][j].z);
        acc[et][j][3] += bf2f(gr[et][j].w) + bf2f(gc[et][j].w);
      }
    }
    gemm_sw<1>(T, TP, w_mes1t, 288, 256, wv, cidx, hi, acc);
  } else {
    gemm_sw<8>(S, SP, w_mes1t, 288, 0,   wv, cidx, hi, acc);
    gemm_sw<1>(T, TP, w_mes1t, 288, 256, wv, cidx, hi, acc);
    __syncthreads();   // S K-reads done before overwriting cols [0,128)
  }
  write_silu_S<SP>(S, acc, wv, cidx, hi);
  __syncthreads();                                   // B2

  // ---------- mes layer 2 -> edge_feat ----------
  acc_bias(mes_b2, wv, hi, acc);
  gemm_sw<4>(S, SP, w_mes2t, 128, 0, wv, cidx, hi, acc);
  uint2 ps[4][2];
  #pragma unroll
  for (int et=0;et<4;++et)
    #pragma unroll
    for (int j=0;j<2;++j){
      f32x4 sv;
      ps[et][j] = silu_pack4(acc[et][j], &sv);
      if constexpr (!GATHER){
        const int e = et*16 + cidx;
        if (e0 + e < E){
          const int f0 = (wv*2+j)*16 + hi*4;
          #pragma unroll
          for (int i=0;i<4;++i)
            atomicAdd(agg + (size_t)cnode[e]*Hdim + f0 + i, sv[i]);
        }
      }
    }
  __syncthreads();                                   // B3 (S K-reads done)
  #pragma unroll
  for (int et=0;et<4;++et)
    #pragma unroll
    for (int j=0;j<2;++j)
      *(uint2*)(S + (size_t)(et*16+cidx)*SP + (wv*2+j)*16 + hi*4) = ps[et][j];
  __syncthreads();                                   // B4

  if constexpr (GATHER){
    // stream feat row to its CSR slot: fully coalesced 64B/4-lane-group
    const int row = tid >> 2, seg = tid & 3;
    if (e0 + row < E){
      const int4* s = (const int4*)(S + (size_t)row*SP + seg*32);
      int4* d = (int4*)(featb + (size_t)pos[e0+row]*Hdim + seg*32);
      d[0]=s[0]; d[1]=s[1]; d[2]=s[2]; d[3]=s[3];
    }
  }

  // ---------- coord layer ----------
  acc_bias(coord_b1, wv, hi, acc);
  gemm_sw<4>(S, SP, w_coord1t, 128, 0, wv, cidx, hi, acc);
  {
    f32x4 cw0 = *(const f32x4*)(coord_w2 + (wv*2+0)*16 + hi*4);
    f32x4 cw1 = *(const f32x4*)(coord_w2 + (wv*2+1)*16 + hi*4);
    #pragma unroll
    for (int et=0;et<4;++et){
      float p = 0.f;
      #pragma unroll
      for (int i=0;i<4;++i)
        p += silu_f(acc[et][0][i])*cw0[i] + silu_f(acc[et][1][i])*cw1[i];
      p += __shfl_xor(p, 16);
      p += __shfl_xor(p, 32);
      if (hi == 0) tvs[wv][et*16+cidx] = p;
    }
  }

  // ---------- edge layer 1 ----------
  acc_bias(edge_b1, wv, hi, acc);
  gemm_sw<4>(S, SP, w_edge1t, 160, 0,   wv, cidx, hi, acc);
  gemm_sw<1>(T, TP, w_edge1t, 160, 128, wv, cidx, hi, acc);
  #pragma unroll
  for (int et=0;et<4;++et)
    #pragma unroll
    for (int j=0;j<2;++j)
      ps[et][j] = silu_pack4(acc[et][j]);
  __syncthreads();                                   // B5 (tvs ready; S K-reads done)
  #pragma unroll
  for (int et=0;et<4;++et)
    #pragma unroll
    for (int j=0;j<2;++j)
      *(uint2*)(S + (size_t)(et*16+cidx)*SP + (wv*2+j)*16 + hi*4) = ps[et][j];
  __syncthreads();                                   // B6

  // ---------- edge layer 2 (no activation) ----------
  acc_bias(edge_b2, wv, hi, acc);
  gemm_sw<4>(S, SP, w_edge2t, 128, 0, wv, cidx, hi, acc);
  #pragma unroll
  for (int et=0;et<4;++et){
    const int e = e0 + et*16 + cidx;
    if (e < E){
      #pragma unroll
      for (int j=0;j<2;++j)
        *(f32x4*)(out_edge + (size_t)e*Hdim + (wv*2+j)*16 + hi*4) = acc[et][j];
    }
  }

  // ---------- coord scatter (after last barrier: contended-atomic drain
  // overlaps block teardown instead of sitting inside the barrier chain) ----------
  if (tid < 192){
    const int le = tid/3, d = tid - le*3;
    if (e0 + le < E){
      const float t4 = tvs[0][le]+tvs[1][le]+tvs[2][le]+tvs[3][le];
      atomicAdd(out_coord + (size_t)cnode[le]*3 + d, cds[le*4+d]*t4);
    }
  }
}

// proj[n][half*128+f] = sum_k h[n][k] * mes_w1[half*128+k][f]   (bf16 out)
__global__ __launch_bounds__(256, 4) void egcl_proj(
    const float* __restrict__ h, const u16* __restrict__ w_mes1t,
    u16* __restrict__ proj, int N)
{
  __shared__ u16 S[64*136];
  const int tid=threadIdx.x, lane=tid&63, wv=tid>>6, cidx=lane&15, hi=lane>>4;
  const int r0 = blockIdx.x*64, half = blockIdx.y;
  {
    const int le = tid>>2, part = tid&3;
    int g = r0 + le; if (g >= N) g = N-1;
    const float* src = h + (size_t)g*Hdim + part*32;
    u16* dst = S + (size_t)le*136 + part*32;
    #pragma unroll
    for (int q=0;q<8;++q){
      float4 v = ((const float4*)src)[q];
      bf16x4 o = {(__bf16)v.x,(__bf16)v.y,(__bf16)v.z,(__bf16)v.w};
      *(bf16x4*)(dst + q*4) = o;
    }
  }
  __syncthreads();
  f32x4 acc[4][2];
  #pragma unroll
  for (int et=0;et<4;++et){ acc[et][0]=(f32x4){0,0,0,0}; acc[et][1]=(f32x4){0,0,0,0}; }
  gemm_sw<4>(S, 136, w_mes1t, 288, half*128, wv, cidx, hi, acc);
  #pragma unroll
  for (int et=0;et<4;++et){
    const int g = r0 + et*16 + cidx;
    if (g < N){
      #pragma unroll
      for (int j=0;j<2;++j)
        *(uint2*)(proj + (size_t)g*256 + half*128 + (wv*2+j)*16 + hi*4) = pack4(acc[et][j]);
    }
  }
}

template<bool GATHER>
__global__ __launch_bounds__(256, 4) void egcl_node(
    const float* __restrict__ h, const float* __restrict__ agg,
    const int* __restrict__ offs, const int* __restrict__ deg,
    const u16* __restrict__ featb,
    const float* __restrict__ node_b1, const float* __restrict__ node_b2,
    const u16* __restrict__ w_node1t, const u16* __restrict__ w_node2t,
    float* __restrict__ out_h, int N)
{
  __shared__ u16 Ab[64*264];
  const int tid=threadIdx.x, lane=tid&63, wv=tid>>6, cidx=lane&15, hi=lane>>4;
  const int r0 = blockIdx.x*64;
  // stage h -> cols [0,128)
  {
    const int le = tid>>2, part = tid&3;
    int g = r0 + le; if (g >= N) g = N-1;
    const float* src = h + (size_t)g*Hdim + part*32;
    u16* dst = Ab + (size_t)le*264 + part*32;
    #pragma unroll
    for (int q=0;q<8;++q){
      float4 v = ((const float4*)src)[q];
      bf16x4 o = {(__bf16)v.x,(__bf16)v.y,(__bf16)v.z,(__bf16)v.w};
      *(bf16x4*)(dst + q*4) = o;
    }
  }
  // agg -> cols [128,256): serial per-group gather was ILP=2; unroll 4 doubles
  // outstanding 64B loads against ~500cy latency (a[32]+4xuint4 ~= 55 live regs,
  // far under the 128 cap; LDS already limits this kernel to 4 blocks/CU)
  if constexpr (GATHER){
    const int le = tid>>2, part = tid&3;
    const int g = r0 + le;
    float a[32];
    #pragma unroll
    for (int q=0;q<32;++q) a[q]=0.f;
    if (g < N){
      const int s = offs[g], dg = deg[g];
      const u16* base = featb + (size_t)s*Hdim + part*32;
      #pragma unroll 4
      for (int r=0;r<dg;++r){
        const uint4* rp = (const uint4*)(base + (size_t)r*Hdim);
        #pragma unroll
        for (int q=0;q<4;++q){
          uint4 w = rp[q];
          a[q*8+0] += bf2f(w.x & 0xffffu); a[q*8+1] += bfhi(w.x);
          a[q*8+2] += bf2f(w.y & 0xffffu); a[q*8+3] += bfhi(w.y);
          a[q*8+4] += bf2f(w.z & 0xffffu); a[q*8+5] += bfhi(w.z);
          a[q*8+6] += bf2f(w.w & 0xffffu); a[q*8+7] += bfhi(w.w);
        }
      }
    }
    u16* dst = Ab + (size_t)le*264 + 128 + part*32;
    #pragma unroll
    for (int q=0;q<8;++q){
      bf16x4 o = {(__bf16)a[q*4+0],(__bf16)a[q*4+1],(__bf16)a[q*4+2],(__bf16)a[q*4+3]};
      *(bf16x4*)(dst + q*4) = o;
    }
  } else {
    const int le = tid>>2, part = tid&3;
    int g = r0 + le; if (g >= N) g = N-1;
    const float* src = agg + (size_t)g*Hdim + part*32;
    u16* dst = Ab + (size_t)le*264 + 128 + part*32;
    #pragma unroll
    for (int q=0;q<8;++q){
      float4 v = ((const float4*)src)[q];
      bf16x4 o = {(__bf16)v.x,(__bf16)v.y,(__bf16)v.z,(__bf16)v.w};
      *(bf16x4*)(dst + q*4) = o;
    }
  }
  __syncthreads();

  f32x4 acc[4][2];
  acc_bias(node_b1, wv, hi, acc);
  gemm_sw<8>(Ab, 264, w_node1t, 256, 0, wv, cidx, hi, acc);
  __syncthreads();
  write_silu_S<264>(Ab, acc, wv, cidx, hi);
  __syncthreads();
  acc_bias(node_b2, wv, hi, acc);
  gemm_sw<4>(Ab, 264, w_node2t, 128, 0, wv, cidx, hi, acc);
  #pragma unroll
  for (int et=0;et<4;++et){
    const int g = r0 + et*16 + cidx;
    if (g < N){
      #pragma unroll
      for (int j=0;j<2;++j){
        const int f0 = (wv*2+j)*16 + hi*4;
        f32x4 hv = *(const f32x4*)(h + (size_t)g*Hdim + f0);
        hv += acc[et][j];
        *(f32x4*)(out_h + (size_t)g*Hdim + f0) = hv;
      }
    }
  }
}

__global__ void egcl_init(const float* __restrict__ coord, float* __restrict__ out_coord,
                          int nc, float* __restrict__ zf, int nzf,
                          int* __restrict__ zi, int nzi)
{
  const int i = blockIdx.x*256 + threadIdx.x;
  if (i < nc) out_coord[i] = coord[i];
  if (zf && i < nzf) zf[i] = 0.f;
  if (zi && i < nzi) zi[i] = 0;
}

// all 7 weight transposes in one launch. mode 1: mes1 remap; mode 2: edge1 remap; 0: plain pad.
__global__ void egcl_wconv7(
    const float* s0, const float* s1, const float* s2, const float* s3,
    const float* s4, const float* s5, const float* s6, u16* __restrict__ dst)
{
  static const int kpads[7]  = {288,128,128,160,128,256,128};
  static const int Ks[7]     = {273,128,128,145,128,256,128};
  static const int modes[7]  = {1,0,0,2,0,0,0};
  const int gi = blockIdx.x*256 + threadIdx.x;
  int w = 0, off = 0, boff = 0;
  #pragma unroll
  for (int t=0;t<7;++t){
    const int sz = 128*kpads[t];
    if (gi >= off && gi < off + sz){ w = t; boff = off; }
    off += sz;
  }
  if (gi >= off) return;
  const float* srcs[7] = {s0,s1,s2,s3,s4,s5,s6};
  const int li = gi - boff;
  const int kpad = kpads[w], K = Ks[w], mode = modes[w];
  const int c = li / kpad, k = li - c*kpad;
  int ks;
  if (mode==1)      ks = (k<256) ? k : (k<272 ? k+1 : (k==272 ? 256 : -1));
  else if (mode==2) ks = (k<128) ? k : (k<144 ? k+1 : (k==144 ? 128 : -1));
  else              ks = (k<K) ? k : -1;
  const float v = (ks>=0) ? srcs[w][(size_t)ks*128 + c] : 0.f;
  *(__bf16*)(dst + gi) = (__bf16)v;
}

__global__ void k_hist(const int* __restrict__ ei, int* __restrict__ hist, int E){
  const int i = blockIdx.x*256 + threadIdx.x;
  if (i < E) atomicAdd(&hist[ei[E + i]], 1);
}
__global__ void k_scan1(const int* __restrict__ hist, int* __restrict__ partial, int N){
  __shared__ int s[256];
  const int t = threadIdx.x, i = blockIdx.x*256 + t;
  s[t] = (i < N) ? hist[i] : 0;
  __syncthreads();
  for (int o=128; o>0; o>>=1){ if (t < o) s[t] += s[t+o]; __syncthreads(); }
  if (t == 0) partial[blockIdx.x] = s[0];
}
// parallel exclusive scan of the per-block partials (G<=256; was a single-thread
// serial loop = ~200 dependent global round-trips ~25-35us; fix saved ~12us, r12)
__global__ void k_scan2(int* __restrict__ partial, int G){
  __shared__ int s[256];
  const int t = threadIdx.x;
  if (G <= 256){
    const int v = (t < G) ? partial[t] : 0;
    s[t] = v;
    __syncthreads();
    for (int o=1; o<256; o<<=1){
      int x = (t >= o) ? s[t-o] : 0;
      __syncthreads();
      s[t] += x;
      __syncthreads();
    }
    if (t < G) partial[t] = s[t] - v;   // exclusive
  } else if (t == 0){
    int run = 0;
    for (int i=0;i<G;++i){ const int v = partial[i]; partial[i] = run; run += v; }
  }
}
__global__ void k_scan3(const int* __restrict__ hist, const int* __restrict__ partial,
                        int* __restrict__ offs, int* __restrict__ cursor, int N){
  __shared__ int s[256];
  const int t = threadIdx.x, i = blockIdx.x*256 + t;
  const int v = (i < N) ? hist[i] : 0;
  s[t] = v;
  __syncthreads();
  for (int o=1; o<256; o<<=1){
    int x = (t >= o) ? s[t-o] : 0;
    __syncthreads();
    s[t] += x;
    __syncthreads();
  }
  const int ex = s[t] - v + partial[blockIdx.x];
  if (i < N){ offs[i] = ex; cursor[i] = ex; }
}
__global__ void k_scatter(const int* __restrict__ ei, int* __restrict__ cursor,
                          int* __restrict__ pos, int E){
  const int i = blockIdx.x*256 + threadIdx.x;
  if (i < E){
    const int c = ei[E + i];
    pos[i] = atomicAdd(&cursor[c], 1);
  }
}

extern "C" void kernel_launch(void* const* d_in, const int* in_sizes, int n_in,
                              void* d_out, int out_size, void* d_ws, size_t ws_size,
                              hipStream_t stream)
{
  const float* h       = (const float*)d_in[0];
  const float* coord   = (const float*)d_in[1];
  const int*   ei      = (const int*)d_in[2];
  const float* ea      = (const float*)d_in[3];
  const float* mes_w1  = (const float*)d_in[4];
  const float* mes_b1  = (const float*)d_in[5];
  const float* mes_w2  = (const float*)d_in[6];
  const float* mes_b2  = (const float*)d_in[7];
  const float* edge_w1 = (const float*)d_in[8];
  const float* edge_b1 = (const float*)d_in[9];
  const float* edge_w2 = (const float*)d_in[10];
  const float* edge_b2 = (const float*)d_in[11];
  const float* node_w1 = (const float*)d_in[12];
  const float* node_b1 = (const float*)d_in[13];
  const float* node_w2 = (const float*)d_in[14];
  const float* node_b2 = (const float*)d_in[15];
  const float* coord_w1= (const float*)d_in[16];
  const float* coord_b1= (const float*)d_in[17];
  const float* coord_w2= (const float*)d_in[18];

  const int N = in_sizes[0] / Hdim;
  const int E = in_sizes[2] / 2;
  const int G1 = (N + 255) / 256;

  char* ws = (char*)d_ws;
  const size_t wtot = (size_t)(288+128+128+160+128+256+128)*128;  // u16 elems
  u16* wbase     = (u16*)ws;
  u16* w_mes1t   = wbase;
  u16* w_mes2t   = w_mes1t  + 128*288;
  u16* w_coord1t = w_mes2t  + 128*128;
  u16* w_edge1t  = w_coord1t+ 128*128;
  u16* w_edge2t  = w_edge1t + 128*160;
  u16* w_node1t  = w_edge2t + 128*128;
  u16* w_node2t  = w_node1t + 128*256;

  auto al = [](size_t x){ return (x + 255) & ~(size_t)255; };
  const size_t base   = al(wtot*2);
  const size_t o_feat = base;
  const size_t o_hist = o_feat + al((size_t)E*Hdim*2);
  const size_t o_offs = o_hist + al((size_t)N*4);
  const size_t o_cur  = o_offs + al((size_t)N*4);
  const size_t o_part = o_cur  + al((size_t)N*4);
  const size_t o_pos  = o_part + al((size_t)G1*4);
  const size_t gather_end = o_pos + al((size_t)E*4);
  const size_t o_proj = gather_end;
  const size_t proj_end = o_proj + (size_t)N*256*2;   // bf16 proj table
  const bool gather = (ws_size >= gather_end);
  const bool proj   = (ws_size >= proj_end);

  float* out_h     = (float*)d_out;
  float* out_coord = out_h + (size_t)N*Hdim;
  float* out_edge  = out_coord + (size_t)N*3;

  const int wblocks = (int)((wtot + 255)/256);
  egcl_wconv7<<<wblocks, 256, 0, stream>>>(mes_w1, mes_w2, coord_w1, edge_w1,
                                           edge_w2, node_w1, node_w2, wbase);

  if (gather){
    u16* featb  = (u16*)(ws + o_feat);
    int* hist   = (int*)(ws + o_hist);
    int* offs   = (int*)(ws + o_offs);
    int* cursor = (int*)(ws + o_cur);
    int* partial= (int*)(ws + o_part);
    int* pos    = (int*)(ws + o_pos);
    u16* projp  = (u16*)(ws + o_proj);

    egcl_init<<<(N*3+255)/256, 256, 0, stream>>>(coord, out_coord, N*3, nullptr, 0, hist, N);
    k_hist<<<(E+255)/256, 256, 0, stream>>>(ei, hist, E);
    k_scan1<<<G1, 256, 0, stream>>>(hist, partial, N);
    k_scan2<<<1, 256, 0, stream>>>(partial, G1);
    k_scan3<<<G1, 256, 0, stream>>>(hist, partial, offs, cursor, N);
    k_scatter<<<(E+255)/256, 256, 0, stream>>>(ei, cursor, pos, E);

    if (proj){
      dim3 pg((N+63)/64, 2);
      egcl_proj<<<pg, 256, 0, stream>>>(h, w_mes1t, projp, N);
      egcl_edge<true,true><<<(E+63)/64, 256, 0, stream>>>(h, coord, ei, ea, projp, pos,
          mes_b1, mes_b2, edge_b1, edge_b2, coord_b1, coord_w2,
          w_mes1t, w_mes2t, w_coord1t, w_edge1t, w_edge2t,
          nullptr, featb, out_coord, out_edge, E);
    } else {
      egcl_edge<false,true><<<(E+63)/64, 256, 0, stream>>>(h, coord, ei, ea, nullptr, pos,
          mes_b1, mes_b2, edge_b1, edge_b2, coord_b1, coord_w2,
          w_mes1t, w_mes2t, w_coord1t, w_edge1t, w_edge2t,
          nullptr, featb, out_coord, out_edge, E);
    }
    egcl_node<true><<<(N+63)/64, 256, 0, stream>>>(h, nullptr, offs, hist, featb,
        node_b1, node_b2, w_node1t, w_node2t, out_h, N);
  } else {
    float* agg = (float*)(ws + base);
    egcl_init<<<(N*Hdim+255)/256, 256, 0, stream>>>(coord, out_coord, N*3, agg, N*Hdim, nullptr, 0);
    egcl_edge<false,false><<<(E+63)/64, 256, 0, stream>>>(h, coord, ei, ea, nullptr, nullptr,
        mes_b1, mes_b2, edge_b1, edge_b2, coord_b1, coord_w2,
        w_mes1t, w_mes2t, w_coord1t, w_edge1t, w_edge2t,
        agg, nullptr, out_coord, out_edge, E);
    egcl_node<false><<<(N+63)/64, 256, 0, stream>>>(h, agg, nullptr, nullptr, nullptr,
        node_b1, node_b2, w_node1t, w_node2t, out_h, N);
  }
}